// Round 22
// baseline (340.192 us; speedup 1.0000x reference)
//
#include <hip/hip_runtime.h>

// ---------------------------------------------------------------------------
// FastRCNN head: RoIPool + FC(25088->4096) + FC(4096->4096) + heads (21/84).
// R22 = R21 (champion, 340.1us) + B prefetch deepened 2->3 iters via 5 LDS
// buffers (80KB B + 64KB A = 144KB <= 160). Mechanism: all waves are
// barrier-locked; in-order vmcnt force-drains B(it) at wait(it-1), so B had
// only ~1 iter of delivery slack — if HBM queueing under full-chip bursts
// exceeds that, every iter blocks. 3-deep gives +1 iter slack at ZERO
// register cost. Prologue order (B0,A0,B1,B2) keeps steady vmcnt(16) exact
// (drain table hand-verified for bodies 0,1,2,steady). Writer at body(it)
// targets the buffer last read at compute(it-2), separated by barrier(it-1).
// ---------------------------------------------------------------------------

typedef __attribute__((ext_vector_type(8))) __bf16 bf16x8;
typedef __attribute__((ext_vector_type(4))) float f32x4;

#define N_ROIS 512
#define FH 50
#define FW 50
#define KK1 25088      // 512*49
#define D1 4096
#define BK 32

__device__ __forceinline__ void gll16(const void* g, void* l) {
  __builtin_amdgcn_global_load_lds(
      (const __attribute__((address_space(1))) void*)g,
      (__attribute__((address_space(3))) void*)l, 16, 0, 0);
}

// ---------------------------------------------------------------------------
// RoIPool: block = (roi, channel-group of 64). 4096 blocks (validated R5-R21).
// ---------------------------------------------------------------------------
__global__ __launch_bounds__(256) void roipool_kernel(
    const float* __restrict__ x, const float* __restrict__ rois,
    __bf16* __restrict__ pooled) {
  const int bid = blockIdx.x;
  const int roi = bid >> 3;
  const int cg = bid & 7;
  const float s = 0.0625f;
  const float r0 = rois[roi * 4 + 0], r1 = rois[roi * 4 + 1];
  const float r2 = rois[roi * 4 + 2], r3 = rois[roi * 4 + 3];
  int x1 = (int)(r0 * s); x1 = min(max(x1, 0), FW - 1);
  int y1 = (int)(r1 * s); y1 = min(max(y1, 0), FH - 1);
  int x2 = (int)(r2 * s); x2 = min(max(x2, 0), FW - 1);
  int y2 = (int)(r3 * s); y2 = min(max(y2, 0), FH - 1);
  const int ww = x2 - x1 + 1, hh = y2 - y1 + 1;
  __shared__ int cs[7], ce[7], rs[7], re[7];
  if (threadIdx.x < 7) {
    int i = threadIdx.x;
    cs[i] = x1 + (i * ww) / 7;
    ce[i] = x1 + ((i + 1) * ww + 6) / 7;
    rs[i] = y1 + (i * hh) / 7;
    re[i] = y1 + ((i + 1) * hh + 6) / 7;
  }
  __syncthreads();
  for (int idx = threadIdx.x; idx < 64 * 49; idx += 256) {
    int cl = idx / 49;
    int p = idx - cl * 49;
    int py = p / 7, px = p - py * 7;
    const int c = cg * 64 + cl;
    const float* base = x + (size_t)c * (FH * FW);
    float m = -3.402823466e38f;
    for (int y = rs[py]; y < re[py]; ++y) {
      const float* rowp = base + y * FW;
      for (int xx = cs[px]; xx < ce[px]; ++xx) m = fmaxf(m, rowp[xx]);
    }
    pooled[(size_t)roi * KK1 + c * 49 + p] = (__bf16)m;
  }
}

// ---------------------------------------------------------------------------
// gemm_pipe: part[z][512][npad] = A[512,K](bf16) @ B[K,N](fp32, N%128==0)
// 256 thr = 4 waves; wave w owns rows w*128..+127 x all 128 cols of the tile.
// z = bid & zmask (XCD-pin), n0 = (bid>>zshift)*128.
// B: 16 gll16/iter into FIVE-buffer LDS (3-iter prefetch depth), XOR-swizzled
//    source, linear dest. A: 8 gll16/wave/iter -> A_lds[2] (R16 swizzle).
// Per-iter wait: vmcnt(16) + s_barrier. nf loop software-pipelined 2-deep.
// ---------------------------------------------------------------------------
template <typename OutT>
__global__ __launch_bounds__(256, 1) void gemm_pipe(
    const __bf16* __restrict__ A, const float* __restrict__ B,
    OutT* __restrict__ part, int N, int K, int kslice, int npad, int zshift) {
  __shared__ float Blds[5][32 * 128];     // 80 KB
  __shared__ __bf16 A_lds[2][512 * 32];   // 64 KB
  const int tid = threadIdx.x;
  const int lane = tid & 63;
  const int w = tid >> 6;  // 0..3
  const int bid = blockIdx.x;
  const int z = bid & ((1 << zshift) - 1);
  const int n0 = (bid >> zshift) * 128;
  const int kbeg = z * kslice;
  const int niters = kslice / BK;  // 98 or 16
  const int fr = lane & 15;
  const int ks = lane >> 4;

  f32x4 acc[8][8];
#pragma unroll
  for (int i = 0; i < 8; ++i)
#pragma unroll
    for (int j = 0; j < 8; ++j) acc[i][j] = (f32x4){0.f, 0.f, 0.f, 0.f};

  // A staging source (R2/R5-validated swizzle)
  const int aswz = (lane & 3) ^ ((lane >> 2) & 3) ^ ((lane >> 4) & 3);
  const __bf16* Asrc =
      A + (size_t)(w * 128 + (lane >> 2)) * K + kbeg + aswz * 8;
  const int aslot = ks ^ ((fr & 3) ^ ((fr >> 2) & 3));

  // B staging: wave w, instr i, lane l -> global row kg + w*8 + 2i + (l>>5),
  // col-group (l&31)^(2w); LDS dest linear (gll16: base + lane*16).
  const int srow = w * 8 + (lane >> 5);
  const float* Bsrc = B + n0 + (((lane & 31) ^ (2 * w)) << 2);

  bf16x8 af[8];  // constant-indexed only -> registers

#define STAGE_A(t)                                                        \
  {                                                                       \
    int off = (t) * BK;                                                   \
    if (off >= kslice) off = 0; /* dup tile; only read when t<niters */   \
    _Pragma("unroll") for (int i = 0; i < 8; ++i) {                       \
      gll16((const void*)(Asrc + (size_t)(i * 16) * K + off),             \
            (void*)&A_lds[(t) & 1][(w * 128 + i * 16) * 32]);             \
    }                                                                     \
  }

#define STAGE_B(t, buf)                                                   \
  {                                                                       \
    int off = (t) * BK;                                                   \
    if (off >= kslice) off = 0; /* dup tile; only read when t<niters */   \
    _Pragma("unroll") for (int i = 0; i < 4; ++i) {                       \
      gll16((const void*)(Bsrc + (size_t)(kbeg + off + srow + 2 * i) * N),\
            (void*)&Blds[buf][(w * 8 + 2 * i) * 128]);                    \
    }                                                                     \
  }

  // raw-f32 read of one nf-block (8 strided LDS scalars) into slot P
#define RD8(P, nf_)                                                       \
  {                                                                       \
    const int base_ = (ks * 8) * 128 +                                    \
        ((((nf_) * 4 + (fr >> 2)) ^ (2 * ks)) << 2) + (fr & 3);           \
    P##0 = bl[base_];        P##1 = bl[base_ + 128];                      \
    P##2 = bl[base_ + 256];  P##3 = bl[base_ + 384];                      \
    P##4 = bl[base_ + 512];  P##5 = bl[base_ + 640];                      \
    P##6 = bl[base_ + 768];  P##7 = bl[base_ + 896];                      \
  }

#define MM8(P, nf_)                                                       \
  {                                                                       \
    bf16x8 bfr;                                                           \
    bfr[0] = (__bf16)P##0; bfr[1] = (__bf16)P##1;                         \
    bfr[2] = (__bf16)P##2; bfr[3] = (__bf16)P##3;                         \
    bfr[4] = (__bf16)P##4; bfr[5] = (__bf16)P##5;                         \
    bfr[6] = (__bf16)P##6; bfr[7] = (__bf16)P##7;                         \
    _Pragma("unroll") for (int mf = 0; mf < 8; ++mf)                      \
        acc[mf][nf_] = __builtin_amdgcn_mfma_f32_16x16x32_bf16(           \
            af[mf], bfr, acc[mf][nf_], 0, 0, 0);                          \
  }

  // prologue (issue order matters for uniform vmcnt(16)): B0, A0, B1, B2.
  STAGE_B(0, 0);
  STAGE_A(0);
  STAGE_B(1, 1);
  STAGE_B(2, 2);

  int rb = 0;  // read buffer  = it % 5
  int wb = 3;  // write buffer = (it+3) % 5
  for (int it = 0; it < niters; ++it) {
    STAGE_A(it + 1);
    STAGE_B(it + 3, wb);
    // steady queue (old->new): B(it)4, A(it)8, B(it+1)4, B(it+2)4,
    // A(it+1)8, B(it+3)4 -> vmcnt(16) drains B(it)+A(it) (and possibly
    // B(it+1)/B(it+2) early — harmless), keeps >= {A(it+1), B(it+3)} in
    // flight. Hand-verified for bodies 0,1,2 with the prologue order above.
    asm volatile("s_waitcnt vmcnt(16)" ::: "memory");
    __builtin_amdgcn_s_barrier();
    __builtin_amdgcn_sched_barrier(0);

    // A frags from LDS (8 x ds_read_b128, 2-way banks)
    {
      const __bf16* al = &A_lds[it & 1][0];
#pragma unroll
      for (int mf = 0; mf < 8; ++mf)
        af[mf] = *(const bf16x8*)(al + (w * 128 + mf * 16 + fr) * 32 +
                                  aslot * 8);
    }
    const float* bl = &Blds[rb][0];
    float rA0, rA1, rA2, rA3, rA4, rA5, rA6, rA7;
    float rB0, rB1, rB2, rB3, rB4, rB5, rB6, rB7;
    float rC0, rC1, rC2, rC3, rC4, rC5, rC6, rC7;
    RD8(rA, 0);
    RD8(rB, 1);
    RD8(rC, 2); MM8(rA, 0);
    RD8(rA, 3); MM8(rB, 1);
    RD8(rB, 4); MM8(rC, 2);
    RD8(rC, 5); MM8(rA, 3);
    RD8(rA, 6); MM8(rB, 4);
    RD8(rB, 7); MM8(rC, 5);
    MM8(rA, 6);
    MM8(rB, 7);

    rb = (rb == 4) ? 0 : rb + 1;
    wb = (wb == 4) ? 0 : wb + 1;
  }
#undef MM8
#undef RD8
#undef STAGE_B
#undef STAGE_A

  // epilogue: C/D layout col = lane&15, row = (lane>>4)*4 + r
  const int r0 = ks * 4;
  OutT* pbase = part + (size_t)z * 512 * npad;
#pragma unroll
  for (int mf = 0; mf < 8; ++mf)
#pragma unroll
    for (int nf = 0; nf < 8; ++nf) {
      const int col = n0 + nf * 16 + fr;
#pragma unroll
      for (int r = 0; r < 4; ++r) {
        const int row = w * 128 + mf * 16 + r0 + r;
        pbase[(size_t)row * npad + col] = (OutT)acc[mf][nf][r];
      }
    }
}

// ---------------------------------------------------------------------------
// gemm_small (R12-validated): barrier-free LDS-free, per-wave 128x64 tile.
// Used for the tiny head GEMMs (handles N < 64 via per-lane guards).
// ---------------------------------------------------------------------------
template <typename OutT>
__global__ __launch_bounds__(256, 1) void gemm_small(
    const __bf16* __restrict__ A, const float* __restrict__ B,
    OutT* __restrict__ part, int N, int K, int kslice, int npad, int zshift) {
  const int tid = threadIdx.x;
  const int lane = tid & 63;
  const int w = tid >> 6;
  const int bid = blockIdx.x;
  const int z = bid & ((1 << zshift) - 1);
  const int n0 = (bid >> zshift) * 64;
  const int kbeg = z * kslice;
  const int niters = kslice / BK;
  const int kmax = kbeg + kslice;
  const int fr = lane & 15;
  const int ks = lane >> 4;
  const int m0 = w * 128;
  const bool fullN = (n0 + 64) <= N;

  f32x4 acc[8][4];
#pragma unroll
  for (int i = 0; i < 8; ++i)
#pragma unroll
    for (int j = 0; j < 4; ++j) acc[i][j] = (f32x4){0.f, 0.f, 0.f, 0.f};

  const __bf16* Abase = A + (size_t)(m0 + fr) * K + ks * 8;
  const size_t Astride = (size_t)16 * K;
  const float* Bbase = B + n0 + fr;

  bf16x8 afA[8], afB[8];
  float bA[32], bB[32];

#define LOAD_A(D, t)                                                     \
  {                                                                      \
    int kk = kbeg + (t) * BK;                                            \
    if (kk >= kmax) kk = kbeg;                                           \
    const __bf16* ap = Abase + kk;                                       \
    _Pragma("unroll") for (int i = 0; i < 8; ++i)                        \
        D[i] = *(const bf16x8*)(ap + (size_t)i * Astride);               \
  }

#define LOAD_B(S, t)                                                     \
  {                                                                      \
    int kg = kbeg + (t) * BK;                                            \
    if (kg >= kmax) kg = kbeg;                                           \
    const float* p = Bbase + (size_t)(kg + ks * 8) * N;                  \
    if (fullN) {                                                         \
      _Pragma("unroll") for (int e = 0; e < 8; ++e) {                    \
        _Pragma("unroll") for (int nf = 0; nf < 4; ++nf)                 \
            S[e * 4 + nf] = p[nf * 16];                                  \
        p += N;                                                          \
      }                                                                  \
    } else {                                                             \
      _Pragma("unroll") for (int e = 0; e < 8; ++e) {                    \
        _Pragma("unroll") for (int nf = 0; nf < 4; ++nf)                 \
            S[e * 4 + nf] =                                              \
                (n0 + nf * 16 + fr < N) ? p[nf * 16] : 0.f;              \
        p += N;                                                          \
      }                                                                  \
    }                                                                    \
  }

#define BODY(it, CA, NA, CB)                                             \
  {                                                                      \
    bf16x8 bfr[4];                                                       \
    _Pragma("unroll") for (int e = 0; e < 8; ++e)                        \
        _Pragma("unroll") for (int nf = 0; nf < 4; ++nf)                 \
            bfr[nf][e] = (__bf16)CB[e * 4 + nf];                         \
    LOAD_B(CB, (it) + 2);                                                \
    LOAD_A(NA, (it) + 1);                                                \
    _Pragma("unroll") for (int nf = 0; nf < 4; ++nf)                     \
        _Pragma("unroll") for (int mf = 0; mf < 8; ++mf)                 \
            acc[mf][nf] = __builtin_amdgcn_mfma_f32_16x16x32_bf16(       \
                CA[mf], bfr[nf], acc[mf][nf], 0, 0, 0);                  \
  }

  LOAD_A(afA, 0);
  LOAD_B(bA, 0);
  LOAD_B(bB, 1);
  for (int it = 0; it < niters; it += 2) {
    BODY(it, afA, afB, bA);
    BODY(it + 1, afB, afA, bB);
  }
#undef BODY
#undef LOAD_B
#undef LOAD_A

  const int r0 = ks * 4;
  OutT* pbase = part + (size_t)z * 512 * npad;
#pragma unroll
  for (int mf = 0; mf < 8; ++mf)
#pragma unroll
    for (int nf = 0; nf < 4; ++nf) {
      const int col = n0 + nf * 16 + fr;
#pragma unroll
      for (int r = 0; r < 4; ++r) {
        const int row = m0 + mf * 16 + r0 + r;
        pbase[(size_t)row * npad + col] = (OutT)acc[mf][nf][r];
      }
    }
}

// sum bf16 split-K partials + bias, relu -> bf16 activations [512][4096]
__global__ __launch_bounds__(256) void reduce_relu_kernel(
    const __bf16* __restrict__ part, const float* __restrict__ bias,
    __bf16* __restrict__ out, int nsplit) {
  const int idx = blockIdx.x * 256 + threadIdx.x;
  const int flat = idx * 8;
  if (flat >= 512 * 4096) return;
  float s[8];
#pragma unroll
  for (int j = 0; j < 8; ++j) s[j] = 0.f;
  for (int sp = 0; sp < nsplit; ++sp) {
    bf16x8 v = *(const bf16x8*)(part + (size_t)sp * (512 * 4096) + flat);
#pragma unroll
    for (int j = 0; j < 8; ++j) s[j] += (float)v[j];
  }
  const int nb = flat & 4095;
  bf16x8 o;
#pragma unroll
  for (int j = 0; j < 8; ++j) {
    float v = s[j] + bias[nb + j];
    o[j] = (__bf16)(v > 0.f ? v : 0.f);
  }
  *(bf16x8*)(out + flat) = o;
}

// final: sum split-K fp32 partials (stride 128) + bias -> d_out fp32
__global__ __launch_bounds__(256) void reduce_out_kernel(
    const float* __restrict__ pc, const float* __restrict__ pr,
    const float* __restrict__ bcls, const float* __restrict__ breg,
    float* __restrict__ out, int nsplit) {
  const int gid = blockIdx.x * 256 + threadIdx.x;
  if (gid >= 512 * 105) return;
  if (gid < 512 * 21) {
    const int m = gid / 21, j = gid - m * 21;
    float s = bcls[j];
    for (int sp = 0; sp < nsplit; ++sp)
      s += pc[(size_t)sp * 512 * 128 + m * 128 + j];
    out[gid] = s;
  } else {
    const int g = gid - 512 * 21;
    const int m = g / 84, j = g - m * 84;
    float s = breg[j];
    for (int sp = 0; sp < nsplit; ++sp)
      s += pr[(size_t)sp * 512 * 128 + m * 128 + j];
    out[gid] = s;
  }
}

extern "C" void kernel_launch(void* const* d_in, const int* in_sizes, int n_in,
                              void* d_out, int out_size, void* d_ws, size_t ws_size,
                              hipStream_t stream) {
  (void)in_sizes; (void)n_in; (void)out_size;
  const float* x    = (const float*)d_in[0];
  const float* rois = (const float*)d_in[2];
  const float* W1   = (const float*)d_in[3];
  const float* b1   = (const float*)d_in[4];
  const float* W2   = (const float*)d_in[5];
  const float* b2   = (const float*)d_in[6];
  const float* Wcls = (const float*)d_in[7];
  const float* bcls = (const float*)d_in[8];
  const float* Wreg = (const float*)d_in[9];
  const float* breg = (const float*)d_in[10];
  float* out = (float*)d_out;

  const size_t pooled_b = (size_t)512 * KK1 * 2;        // 25,690,112
  const size_t act_b = (size_t)512 * D1 * 2;            // 4 MiB
  const size_t need8 = pooled_b + (size_t)8 * act_b + 2 * act_b;
  const int ns = (ws_size >= need8) ? 8 : 2;            // ws ~1.6GB: ns=8
  const int zshift = (ns == 8) ? 3 : 1;

  char* ws = (char*)d_ws;
  __bf16* pooled = (__bf16*)ws;
  __bf16* part1 = (__bf16*)(ws + pooled_b);             // ns * 4MiB
  __bf16* f1 = (__bf16*)(ws + pooled_b + (size_t)ns * act_b);
  __bf16* f2 = (__bf16*)(ws + pooled_b + (size_t)ns * act_b + act_b);
  __bf16* part2 = (__bf16*)ws;                          // alias dead pooled+part1
  float* pcls = (float*)ws;                             // heads phase aliases
  float* preg = (float*)(ws + (size_t)64 * 512 * 128 * 4);  // +16.8MB

  // 1) RoIPool -> pooled bf16 [512, 25088]
  roipool_kernel<<<N_ROIS * 8, 256, 0, stream>>>(x, rois, pooled);

  // 2) GEMM1: pooled @ W1[25088,4096]; W1 read exactly once; z-pinned XCDs
  gemm_pipe<__bf16><<<32 * ns, 256, 0, stream>>>(
      pooled, W1, part1, 4096, KK1, KK1 / ns, 4096, zshift);
  reduce_relu_kernel<<<1024, 256, 0, stream>>>(part1, b1, f1, ns);

  // 3) GEMM2: f1 @ W2[4096,4096]
  gemm_pipe<__bf16><<<32 * ns, 256, 0, stream>>>(
      f1, W2, part2, 4096, 4096, 4096 / ns, 4096, zshift);
  reduce_relu_kernel<<<1024, 256, 0, stream>>>(part2, b2, f2, ns);

  // 4) heads via gemm_small (N<128-safe), split-K=64
  gemm_small<float><<<64, 256, 0, stream>>>(
      f2, Wcls, pcls, 21, 4096, 64, 128, 6);
  gemm_small<float><<<128, 256, 0, stream>>>(
      f2, Wreg, preg, 84, 4096, 64, 128, 6);
  reduce_out_kernel<<<(512 * 105 + 255) / 256, 256, 0, stream>>>(
      pcls, preg, bcls, breg, out, 64);
}

// Round 23
// 333.198 us; speedup vs baseline: 1.0210x; 1.0210x over previous
//
#include <hip/hip_runtime.h>

// ---------------------------------------------------------------------------
// FastRCNN head: RoIPool + FC(25088->4096) + FC(4096->4096) + heads (21/84).
// R23 = R22 champion (340.1us, reproduced 3x) + roipool occupancy boost:
// 8192 blocks (roi x 16 groups of 32 channels) — roipool is latency-bound
// (94 GB/s, 12.7% occupancy); R4 showed block-count is its lever.
// GEMM structure is converged (9 variants, 3 surgical nulls): LDS-port-bound
// on the forced fp32->bf16 k-transpose; pre-pack escape is byte-neutral.
// ---------------------------------------------------------------------------

typedef __attribute__((ext_vector_type(8))) __bf16 bf16x8;
typedef __attribute__((ext_vector_type(4))) float f32x4;

#define N_ROIS 512
#define FH 50
#define FW 50
#define KK1 25088      // 512*49
#define D1 4096
#define BK 32

__device__ __forceinline__ void gll16(const void* g, void* l) {
  __builtin_amdgcn_global_load_lds(
      (const __attribute__((address_space(1))) void*)g,
      (__attribute__((address_space(3))) void*)l, 16, 0, 0);
}

// ---------------------------------------------------------------------------
// RoIPool: block = (roi, channel-group of 32). 8192 blocks for latency hiding.
// ---------------------------------------------------------------------------
__global__ __launch_bounds__(256) void roipool_kernel(
    const float* __restrict__ x, const float* __restrict__ rois,
    __bf16* __restrict__ pooled) {
  const int bid = blockIdx.x;
  const int roi = bid >> 4;
  const int cg = bid & 15;
  const float s = 0.0625f;
  const float r0 = rois[roi * 4 + 0], r1 = rois[roi * 4 + 1];
  const float r2 = rois[roi * 4 + 2], r3 = rois[roi * 4 + 3];
  int x1 = (int)(r0 * s); x1 = min(max(x1, 0), FW - 1);
  int y1 = (int)(r1 * s); y1 = min(max(y1, 0), FH - 1);
  int x2 = (int)(r2 * s); x2 = min(max(x2, 0), FW - 1);
  int y2 = (int)(r3 * s); y2 = min(max(y2, 0), FH - 1);
  const int ww = x2 - x1 + 1, hh = y2 - y1 + 1;
  __shared__ int cs[7], ce[7], rs[7], re[7];
  if (threadIdx.x < 7) {
    int i = threadIdx.x;
    cs[i] = x1 + (i * ww) / 7;
    ce[i] = x1 + ((i + 1) * ww + 6) / 7;
    rs[i] = y1 + (i * hh) / 7;
    re[i] = y1 + ((i + 1) * hh + 6) / 7;
  }
  __syncthreads();
  for (int idx = threadIdx.x; idx < 32 * 49; idx += 256) {
    int cl = idx / 49;
    int p = idx - cl * 49;
    int py = p / 7, px = p - py * 7;
    const int c = cg * 32 + cl;
    const float* base = x + (size_t)c * (FH * FW);
    float m = -3.402823466e38f;
    for (int y = rs[py]; y < re[py]; ++y) {
      const float* rowp = base + y * FW;
      for (int xx = cs[px]; xx < ce[px]; ++xx) m = fmaxf(m, rowp[xx]);
    }
    pooled[(size_t)roi * KK1 + c * 49 + p] = (__bf16)m;
  }
}

// ---------------------------------------------------------------------------
// gemm_pipe (champion, byte-identical to R22): part[z][512][npad] =
// A[512,K](bf16) @ B[K,N](fp32, N%128==0). 256 thr = 4 waves; wave w owns
// rows w*128..+127 x all 128 cols. z = bid & zmask (XCD-pin).
// B: 16 gll16/iter into 5-buffer LDS; A: 8 gll16/wave/iter -> A_lds[2].
// Per-iter wait: vmcnt(16) + s_barrier. nf loop software-pipelined 2-deep.
// ---------------------------------------------------------------------------
template <typename OutT>
__global__ __launch_bounds__(256, 1) void gemm_pipe(
    const __bf16* __restrict__ A, const float* __restrict__ B,
    OutT* __restrict__ part, int N, int K, int kslice, int npad, int zshift) {
  __shared__ float Blds[5][32 * 128];     // 80 KB
  __shared__ __bf16 A_lds[2][512 * 32];   // 64 KB
  const int tid = threadIdx.x;
  const int lane = tid & 63;
  const int w = tid >> 6;  // 0..3
  const int bid = blockIdx.x;
  const int z = bid & ((1 << zshift) - 1);
  const int n0 = (bid >> zshift) * 128;
  const int kbeg = z * kslice;
  const int niters = kslice / BK;  // 98 or 16
  const int fr = lane & 15;
  const int ks = lane >> 4;

  f32x4 acc[8][8];
#pragma unroll
  for (int i = 0; i < 8; ++i)
#pragma unroll
    for (int j = 0; j < 8; ++j) acc[i][j] = (f32x4){0.f, 0.f, 0.f, 0.f};

  const int aswz = (lane & 3) ^ ((lane >> 2) & 3) ^ ((lane >> 4) & 3);
  const __bf16* Asrc =
      A + (size_t)(w * 128 + (lane >> 2)) * K + kbeg + aswz * 8;
  const int aslot = ks ^ ((fr & 3) ^ ((fr >> 2) & 3));

  const int srow = w * 8 + (lane >> 5);
  const float* Bsrc = B + n0 + (((lane & 31) ^ (2 * w)) << 2);

  bf16x8 af[8];  // constant-indexed only -> registers

#define STAGE_A(t)                                                        \
  {                                                                       \
    int off = (t) * BK;                                                   \
    if (off >= kslice) off = 0;                                           \
    _Pragma("unroll") for (int i = 0; i < 8; ++i) {                       \
      gll16((const void*)(Asrc + (size_t)(i * 16) * K + off),             \
            (void*)&A_lds[(t) & 1][(w * 128 + i * 16) * 32]);             \
    }                                                                     \
  }

#define STAGE_B(t, buf)                                                   \
  {                                                                       \
    int off = (t) * BK;                                                   \
    if (off >= kslice) off = 0;                                           \
    _Pragma("unroll") for (int i = 0; i < 4; ++i) {                       \
      gll16((const void*)(Bsrc + (size_t)(kbeg + off + srow + 2 * i) * N),\
            (void*)&Blds[buf][(w * 8 + 2 * i) * 128]);                    \
    }                                                                     \
  }

#define RD8(P, nf_)                                                       \
  {                                                                       \
    const int base_ = (ks * 8) * 128 +                                    \
        ((((nf_) * 4 + (fr >> 2)) ^ (2 * ks)) << 2) + (fr & 3);           \
    P##0 = bl[base_];        P##1 = bl[base_ + 128];                      \
    P##2 = bl[base_ + 256];  P##3 = bl[base_ + 384];                      \
    P##4 = bl[base_ + 512];  P##5 = bl[base_ + 640];                      \
    P##6 = bl[base_ + 768];  P##7 = bl[base_ + 896];                      \
  }

#define MM8(P, nf_)                                                       \
  {                                                                       \
    bf16x8 bfr;                                                           \
    bfr[0] = (__bf16)P##0; bfr[1] = (__bf16)P##1;                         \
    bfr[2] = (__bf16)P##2; bfr[3] = (__bf16)P##3;                         \
    bfr[4] = (__bf16)P##4; bfr[5] = (__bf16)P##5;                         \
    bfr[6] = (__bf16)P##6; bfr[7] = (__bf16)P##7;                         \
    _Pragma("unroll") for (int mf = 0; mf < 8; ++mf)                      \
        acc[mf][nf_] = __builtin_amdgcn_mfma_f32_16x16x32_bf16(           \
            af[mf], bfr, acc[mf][nf_], 0, 0, 0);                          \
  }

  // prologue (issue order keeps steady vmcnt(16) exact): B0, A0, B1, B2.
  STAGE_B(0, 0);
  STAGE_A(0);
  STAGE_B(1, 1);
  STAGE_B(2, 2);

  int rb = 0;  // read buffer  = it % 5
  int wb = 3;  // write buffer = (it+3) % 5
  for (int it = 0; it < niters; ++it) {
    STAGE_A(it + 1);
    STAGE_B(it + 3, wb);
    asm volatile("s_waitcnt vmcnt(16)" ::: "memory");
    __builtin_amdgcn_s_barrier();
    __builtin_amdgcn_sched_barrier(0);

    {
      const __bf16* al = &A_lds[it & 1][0];
#pragma unroll
      for (int mf = 0; mf < 8; ++mf)
        af[mf] = *(const bf16x8*)(al + (w * 128 + mf * 16 + fr) * 32 +
                                  aslot * 8);
    }
    const float* bl = &Blds[rb][0];
    float rA0, rA1, rA2, rA3, rA4, rA5, rA6, rA7;
    float rB0, rB1, rB2, rB3, rB4, rB5, rB6, rB7;
    float rC0, rC1, rC2, rC3, rC4, rC5, rC6, rC7;
    RD8(rA, 0);
    RD8(rB, 1);
    RD8(rC, 2); MM8(rA, 0);
    RD8(rA, 3); MM8(rB, 1);
    RD8(rB, 4); MM8(rC, 2);
    RD8(rC, 5); MM8(rA, 3);
    RD8(rA, 6); MM8(rB, 4);
    RD8(rB, 7); MM8(rC, 5);
    MM8(rA, 6);
    MM8(rB, 7);

    rb = (rb == 4) ? 0 : rb + 1;
    wb = (wb == 4) ? 0 : wb + 1;
  }
#undef MM8
#undef RD8
#undef STAGE_B
#undef STAGE_A

  // epilogue: C/D layout col = lane&15, row = (lane>>4)*4 + r
  const int r0 = ks * 4;
  OutT* pbase = part + (size_t)z * 512 * npad;
#pragma unroll
  for (int mf = 0; mf < 8; ++mf)
#pragma unroll
    for (int nf = 0; nf < 8; ++nf) {
      const int col = n0 + nf * 16 + fr;
#pragma unroll
      for (int r = 0; r < 4; ++r) {
        const int row = w * 128 + mf * 16 + r0 + r;
        pbase[(size_t)row * npad + col] = (OutT)acc[mf][nf][r];
      }
    }
}

// ---------------------------------------------------------------------------
// gemm_small (R12-validated): barrier-free LDS-free, per-wave 128x64 tile.
// ---------------------------------------------------------------------------
template <typename OutT>
__global__ __launch_bounds__(256, 1) void gemm_small(
    const __bf16* __restrict__ A, const float* __restrict__ B,
    OutT* __restrict__ part, int N, int K, int kslice, int npad, int zshift) {
  const int tid = threadIdx.x;
  const int lane = tid & 63;
  const int w = tid >> 6;
  const int bid = blockIdx.x;
  const int z = bid & ((1 << zshift) - 1);
  const int n0 = (bid >> zshift) * 64;
  const int kbeg = z * kslice;
  const int niters = kslice / BK;
  const int kmax = kbeg + kslice;
  const int fr = lane & 15;
  const int ks = lane >> 4;
  const int m0 = w * 128;
  const bool fullN = (n0 + 64) <= N;

  f32x4 acc[8][4];
#pragma unroll
  for (int i = 0; i < 8; ++i)
#pragma unroll
    for (int j = 0; j < 4; ++j) acc[i][j] = (f32x4){0.f, 0.f, 0.f, 0.f};

  const __bf16* Abase = A + (size_t)(m0 + fr) * K + ks * 8;
  const size_t Astride = (size_t)16 * K;
  const float* Bbase = B + n0 + fr;

  bf16x8 afA[8], afB[8];
  float bA[32], bB[32];

#define LOAD_A(D, t)                                                     \
  {                                                                      \
    int kk = kbeg + (t) * BK;                                            \
    if (kk >= kmax) kk = kbeg;                                           \
    const __bf16* ap = Abase + kk;                                       \
    _Pragma("unroll") for (int i = 0; i < 8; ++i)                        \
        D[i] = *(const bf16x8*)(ap + (size_t)i * Astride);               \
  }

#define LOAD_B(S, t)                                                     \
  {                                                                      \
    int kg = kbeg + (t) * BK;                                            \
    if (kg >= kmax) kg = kbeg;                                           \
    const float* p = Bbase + (size_t)(kg + ks * 8) * N;                  \
    if (fullN) {                                                         \
      _Pragma("unroll") for (int e = 0; e < 8; ++e) {                    \
        _Pragma("unroll") for (int nf = 0; nf < 4; ++nf)                 \
            S[e * 4 + nf] = p[nf * 16];                                  \
        p += N;                                                          \
      }                                                                  \
    } else {                                                             \
      _Pragma("unroll") for (int e = 0; e < 8; ++e) {                    \
        _Pragma("unroll") for (int nf = 0; nf < 4; ++nf)                 \
            S[e * 4 + nf] =                                              \
                (n0 + nf * 16 + fr < N) ? p[nf * 16] : 0.f;              \
        p += N;                                                          \
      }                                                                  \
    }                                                                    \
  }

#define BODY(it, CA, NA, CB)                                             \
  {                                                                      \
    bf16x8 bfr[4];                                                       \
    _Pragma("unroll") for (int e = 0; e < 8; ++e)                        \
        _Pragma("unroll") for (int nf = 0; nf < 4; ++nf)                 \
            bfr[nf][e] = (__bf16)CB[e * 4 + nf];                         \
    LOAD_B(CB, (it) + 2);                                                \
    LOAD_A(NA, (it) + 1);                                                \
    _Pragma("unroll") for (int nf = 0; nf < 4; ++nf)                     \
        _Pragma("unroll") for (int mf = 0; mf < 8; ++mf)                 \
            acc[mf][nf] = __builtin_amdgcn_mfma_f32_16x16x32_bf16(       \
                CA[mf], bfr[nf], acc[mf][nf], 0, 0, 0);                  \
  }

  LOAD_A(afA, 0);
  LOAD_B(bA, 0);
  LOAD_B(bB, 1);
  for (int it = 0; it < niters; it += 2) {
    BODY(it, afA, afB, bA);
    BODY(it + 1, afB, afA, bB);
  }
#undef BODY
#undef LOAD_B
#undef LOAD_A

  const int r0 = ks * 4;
  OutT* pbase = part + (size_t)z * 512 * npad;
#pragma unroll
  for (int mf = 0; mf < 8; ++mf)
#pragma unroll
    for (int nf = 0; nf < 4; ++nf) {
      const int col = n0 + nf * 16 + fr;
#pragma unroll
      for (int r = 0; r < 4; ++r) {
        const int row = m0 + mf * 16 + r0 + r;
        pbase[(size_t)row * npad + col] = (OutT)acc[mf][nf][r];
      }
    }
}

// sum bf16 split-K partials + bias, relu -> bf16 activations [512][4096]
__global__ __launch_bounds__(256) void reduce_relu_kernel(
    const __bf16* __restrict__ part, const float* __restrict__ bias,
    __bf16* __restrict__ out, int nsplit) {
  const int idx = blockIdx.x * 256 + threadIdx.x;
  const int flat = idx * 8;
  if (flat >= 512 * 4096) return;
  float s[8];
#pragma unroll
  for (int j = 0; j < 8; ++j) s[j] = 0.f;
  for (int sp = 0; sp < nsplit; ++sp) {
    bf16x8 v = *(const bf16x8*)(part + (size_t)sp * (512 * 4096) + flat);
#pragma unroll
    for (int j = 0; j < 8; ++j) s[j] += (float)v[j];
  }
  const int nb = flat & 4095;
  bf16x8 o;
#pragma unroll
  for (int j = 0; j < 8; ++j) {
    float v = s[j] + bias[nb + j];
    o[j] = (__bf16)(v > 0.f ? v : 0.f);
  }
  *(bf16x8*)(out + flat) = o;
}

// final: sum split-K fp32 partials (stride 128) + bias -> d_out fp32
__global__ __launch_bounds__(256) void reduce_out_kernel(
    const float* __restrict__ pc, const float* __restrict__ pr,
    const float* __restrict__ bcls, const float* __restrict__ breg,
    float* __restrict__ out, int nsplit) {
  const int gid = blockIdx.x * 256 + threadIdx.x;
  if (gid >= 512 * 105) return;
  if (gid < 512 * 21) {
    const int m = gid / 21, j = gid - m * 21;
    float s = bcls[j];
    for (int sp = 0; sp < nsplit; ++sp)
      s += pc[(size_t)sp * 512 * 128 + m * 128 + j];
    out[gid] = s;
  } else {
    const int g = gid - 512 * 21;
    const int m = g / 84, j = g - m * 84;
    float s = breg[j];
    for (int sp = 0; sp < nsplit; ++sp)
      s += pr[(size_t)sp * 512 * 128 + m * 128 + j];
    out[gid] = s;
  }
}

extern "C" void kernel_launch(void* const* d_in, const int* in_sizes, int n_in,
                              void* d_out, int out_size, void* d_ws, size_t ws_size,
                              hipStream_t stream) {
  (void)in_sizes; (void)n_in; (void)out_size;
  const float* x    = (const float*)d_in[0];
  const float* rois = (const float*)d_in[2];
  const float* W1   = (const float*)d_in[3];
  const float* b1   = (const float*)d_in[4];
  const float* W2   = (const float*)d_in[5];
  const float* b2   = (const float*)d_in[6];
  const float* Wcls = (const float*)d_in[7];
  const float* bcls = (const float*)d_in[8];
  const float* Wreg = (const float*)d_in[9];
  const float* breg = (const float*)d_in[10];
  float* out = (float*)d_out;

  const size_t pooled_b = (size_t)512 * KK1 * 2;        // 25,690,112
  const size_t act_b = (size_t)512 * D1 * 2;            // 4 MiB
  const size_t need8 = pooled_b + (size_t)8 * act_b + 2 * act_b;
  const int ns = (ws_size >= need8) ? 8 : 2;            // ws ~1.6GB: ns=8
  const int zshift = (ns == 8) ? 3 : 1;

  char* ws = (char*)d_ws;
  __bf16* pooled = (__bf16*)ws;
  __bf16* part1 = (__bf16*)(ws + pooled_b);             // ns * 4MiB
  __bf16* f1 = (__bf16*)(ws + pooled_b + (size_t)ns * act_b);
  __bf16* f2 = (__bf16*)(ws + pooled_b + (size_t)ns * act_b + act_b);
  __bf16* part2 = (__bf16*)ws;                          // alias dead pooled+part1
  float* pcls = (float*)ws;                             // heads phase aliases
  float* preg = (float*)(ws + (size_t)64 * 512 * 128 * 4);  // +16.8MB

  // 1) RoIPool -> pooled bf16 [512, 25088]; 8192 blocks for latency hiding
  roipool_kernel<<<N_ROIS * 16, 256, 0, stream>>>(x, rois, pooled);

  // 2) GEMM1: pooled @ W1[25088,4096]; W1 read exactly once; z-pinned XCDs
  gemm_pipe<__bf16><<<32 * ns, 256, 0, stream>>>(
      pooled, W1, part1, 4096, KK1, KK1 / ns, 4096, zshift);
  reduce_relu_kernel<<<1024, 256, 0, stream>>>(part1, b1, f1, ns);

  // 3) GEMM2: f1 @ W2[4096,4096]
  gemm_pipe<__bf16><<<32 * ns, 256, 0, stream>>>(
      f1, W2, part2, 4096, 4096, 4096 / ns, 4096, zshift);
  reduce_relu_kernel<<<1024, 256, 0, stream>>>(part2, b2, f2, ns);

  // 4) heads via gemm_small (N<128-safe), split-K=64
  gemm_small<float><<<64, 256, 0, stream>>>(
      f2, Wcls, pcls, 21, 4096, 64, 128, 6);
  gemm_small<float><<<128, 256, 0, stream>>>(
      f2, Wreg, preg, 84, 4096, 64, 128, 6);
  reduce_out_kernel<<<(512 * 105 + 255) / 256, 256, 0, stream>>>(
      pcls, preg, bcls, breg, out, 64);
}

// Round 24
// 330.741 us; speedup vs baseline: 1.0286x; 1.0074x over previous
//
#include <hip/hip_runtime.h>

// ---------------------------------------------------------------------------
// FastRCNN head: RoIPool + FC(25088->4096) + FC(4096->4096) + heads (21/84).
// R24 = R23 champion (333.2us) + roipool split once more: 16384 blocks
// (roi x 32 groups of 16 channels). Same confirmed mechanism (latency-bound
// serial-window loops; occupancy is the lever: R4 271->25, R23 25->~18).
// GEMM path byte-identical to the 3x-reproduced champion; structure converged
// (9 designs + 3 surgical nulls; LDS-port-bound on the fp32->bf16 transpose).
// ---------------------------------------------------------------------------

typedef __attribute__((ext_vector_type(8))) __bf16 bf16x8;
typedef __attribute__((ext_vector_type(4))) float f32x4;

#define N_ROIS 512
#define FH 50
#define FW 50
#define KK1 25088      // 512*49
#define D1 4096
#define BK 32

__device__ __forceinline__ void gll16(const void* g, void* l) {
  __builtin_amdgcn_global_load_lds(
      (const __attribute__((address_space(1))) void*)g,
      (__attribute__((address_space(3))) void*)l, 16, 0, 0);
}

// ---------------------------------------------------------------------------
// RoIPool: block = (roi, channel-group of 16). 16384 blocks, latency hiding.
// ---------------------------------------------------------------------------
__global__ __launch_bounds__(256) void roipool_kernel(
    const float* __restrict__ x, const float* __restrict__ rois,
    __bf16* __restrict__ pooled) {
  const int bid = blockIdx.x;
  const int roi = bid >> 5;
  const int cg = bid & 31;
  const float s = 0.0625f;
  const float r0 = rois[roi * 4 + 0], r1 = rois[roi * 4 + 1];
  const float r2 = rois[roi * 4 + 2], r3 = rois[roi * 4 + 3];
  int x1 = (int)(r0 * s); x1 = min(max(x1, 0), FW - 1);
  int y1 = (int)(r1 * s); y1 = min(max(y1, 0), FH - 1);
  int x2 = (int)(r2 * s); x2 = min(max(x2, 0), FW - 1);
  int y2 = (int)(r3 * s); y2 = min(max(y2, 0), FH - 1);
  const int ww = x2 - x1 + 1, hh = y2 - y1 + 1;
  __shared__ int cs[7], ce[7], rs[7], re[7];
  if (threadIdx.x < 7) {
    int i = threadIdx.x;
    cs[i] = x1 + (i * ww) / 7;
    ce[i] = x1 + ((i + 1) * ww + 6) / 7;
    rs[i] = y1 + (i * hh) / 7;
    re[i] = y1 + ((i + 1) * hh + 6) / 7;
  }
  __syncthreads();
  for (int idx = threadIdx.x; idx < 16 * 49; idx += 256) {
    int cl = idx / 49;
    int p = idx - cl * 49;
    int py = p / 7, px = p - py * 7;
    const int c = cg * 16 + cl;
    const float* base = x + (size_t)c * (FH * FW);
    float m = -3.402823466e38f;
    for (int y = rs[py]; y < re[py]; ++y) {
      const float* rowp = base + y * FW;
      for (int xx = cs[px]; xx < ce[px]; ++xx) m = fmaxf(m, rowp[xx]);
    }
    pooled[(size_t)roi * KK1 + c * 49 + p] = (__bf16)m;
  }
}

// ---------------------------------------------------------------------------
// gemm_pipe (champion, byte-identical to R22/R23): part[z][512][npad] =
// A[512,K](bf16) @ B[K,N](fp32, N%128==0). 256 thr = 4 waves; wave w owns
// rows w*128..+127 x all 128 cols. z = bid & zmask (XCD-pin).
// B: 16 gll16/iter into 5-buffer LDS; A: 8 gll16/wave/iter -> A_lds[2].
// Per-iter wait: vmcnt(16) + s_barrier. nf loop software-pipelined 2-deep.
// ---------------------------------------------------------------------------
template <typename OutT>
__global__ __launch_bounds__(256, 1) void gemm_pipe(
    const __bf16* __restrict__ A, const float* __restrict__ B,
    OutT* __restrict__ part, int N, int K, int kslice, int npad, int zshift) {
  __shared__ float Blds[5][32 * 128];     // 80 KB
  __shared__ __bf16 A_lds[2][512 * 32];   // 64 KB
  const int tid = threadIdx.x;
  const int lane = tid & 63;
  const int w = tid >> 6;  // 0..3
  const int bid = blockIdx.x;
  const int z = bid & ((1 << zshift) - 1);
  const int n0 = (bid >> zshift) * 128;
  const int kbeg = z * kslice;
  const int niters = kslice / BK;  // 98 or 16
  const int fr = lane & 15;
  const int ks = lane >> 4;

  f32x4 acc[8][8];
#pragma unroll
  for (int i = 0; i < 8; ++i)
#pragma unroll
    for (int j = 0; j < 8; ++j) acc[i][j] = (f32x4){0.f, 0.f, 0.f, 0.f};

  const int aswz = (lane & 3) ^ ((lane >> 2) & 3) ^ ((lane >> 4) & 3);
  const __bf16* Asrc =
      A + (size_t)(w * 128 + (lane >> 2)) * K + kbeg + aswz * 8;
  const int aslot = ks ^ ((fr & 3) ^ ((fr >> 2) & 3));

  const int srow = w * 8 + (lane >> 5);
  const float* Bsrc = B + n0 + (((lane & 31) ^ (2 * w)) << 2);

  bf16x8 af[8];  // constant-indexed only -> registers

#define STAGE_A(t)                                                        \
  {                                                                       \
    int off = (t) * BK;                                                   \
    if (off >= kslice) off = 0;                                           \
    _Pragma("unroll") for (int i = 0; i < 8; ++i) {                       \
      gll16((const void*)(Asrc + (size_t)(i * 16) * K + off),             \
            (void*)&A_lds[(t) & 1][(w * 128 + i * 16) * 32]);             \
    }                                                                     \
  }

#define STAGE_B(t, buf)                                                   \
  {                                                                       \
    int off = (t) * BK;                                                   \
    if (off >= kslice) off = 0;                                           \
    _Pragma("unroll") for (int i = 0; i < 4; ++i) {                       \
      gll16((const void*)(Bsrc + (size_t)(kbeg + off + srow + 2 * i) * N),\
            (void*)&Blds[buf][(w * 8 + 2 * i) * 128]);                    \
    }                                                                     \
  }

#define RD8(P, nf_)                                                       \
  {                                                                       \
    const int base_ = (ks * 8) * 128 +                                    \
        ((((nf_) * 4 + (fr >> 2)) ^ (2 * ks)) << 2) + (fr & 3);           \
    P##0 = bl[base_];        P##1 = bl[base_ + 128];                      \
    P##2 = bl[base_ + 256];  P##3 = bl[base_ + 384];                      \
    P##4 = bl[base_ + 512];  P##5 = bl[base_ + 640];                      \
    P##6 = bl[base_ + 768];  P##7 = bl[base_ + 896];                      \
  }

#define MM8(P, nf_)                                                       \
  {                                                                       \
    bf16x8 bfr;                                                           \
    bfr[0] = (__bf16)P##0; bfr[1] = (__bf16)P##1;                         \
    bfr[2] = (__bf16)P##2; bfr[3] = (__bf16)P##3;                         \
    bfr[4] = (__bf16)P##4; bfr[5] = (__bf16)P##5;                         \
    bfr[6] = (__bf16)P##6; bfr[7] = (__bf16)P##7;                         \
    _Pragma("unroll") for (int mf = 0; mf < 8; ++mf)                      \
        acc[mf][nf_] = __builtin_amdgcn_mfma_f32_16x16x32_bf16(           \
            af[mf], bfr, acc[mf][nf_], 0, 0, 0);                          \
  }

  // prologue (issue order keeps steady vmcnt(16) exact): B0, A0, B1, B2.
  STAGE_B(0, 0);
  STAGE_A(0);
  STAGE_B(1, 1);
  STAGE_B(2, 2);

  int rb = 0;  // read buffer  = it % 5
  int wb = 3;  // write buffer = (it+3) % 5
  for (int it = 0; it < niters; ++it) {
    STAGE_A(it + 1);
    STAGE_B(it + 3, wb);
    asm volatile("s_waitcnt vmcnt(16)" ::: "memory");
    __builtin_amdgcn_s_barrier();
    __builtin_amdgcn_sched_barrier(0);

    {
      const __bf16* al = &A_lds[it & 1][0];
#pragma unroll
      for (int mf = 0; mf < 8; ++mf)
        af[mf] = *(const bf16x8*)(al + (w * 128 + mf * 16 + fr) * 32 +
                                  aslot * 8);
    }
    const float* bl = &Blds[rb][0];
    float rA0, rA1, rA2, rA3, rA4, rA5, rA6, rA7;
    float rB0, rB1, rB2, rB3, rB4, rB5, rB6, rB7;
    float rC0, rC1, rC2, rC3, rC4, rC5, rC6, rC7;
    RD8(rA, 0);
    RD8(rB, 1);
    RD8(rC, 2); MM8(rA, 0);
    RD8(rA, 3); MM8(rB, 1);
    RD8(rB, 4); MM8(rC, 2);
    RD8(rC, 5); MM8(rA, 3);
    RD8(rA, 6); MM8(rB, 4);
    RD8(rB, 7); MM8(rC, 5);
    MM8(rA, 6);
    MM8(rB, 7);

    rb = (rb == 4) ? 0 : rb + 1;
    wb = (wb == 4) ? 0 : wb + 1;
  }
#undef MM8
#undef RD8
#undef STAGE_B
#undef STAGE_A

  // epilogue: C/D layout col = lane&15, row = (lane>>4)*4 + r
  const int r0 = ks * 4;
  OutT* pbase = part + (size_t)z * 512 * npad;
#pragma unroll
  for (int mf = 0; mf < 8; ++mf)
#pragma unroll
    for (int nf = 0; nf < 8; ++nf) {
      const int col = n0 + nf * 16 + fr;
#pragma unroll
      for (int r = 0; r < 4; ++r) {
        const int row = w * 128 + mf * 16 + r0 + r;
        pbase[(size_t)row * npad + col] = (OutT)acc[mf][nf][r];
      }
    }
}

// ---------------------------------------------------------------------------
// gemm_small (R12-validated): barrier-free LDS-free, per-wave 128x64 tile.
// ---------------------------------------------------------------------------
template <typename OutT>
__global__ __launch_bounds__(256, 1) void gemm_small(
    const __bf16* __restrict__ A, const float* __restrict__ B,
    OutT* __restrict__ part, int N, int K, int kslice, int npad, int zshift) {
  const int tid = threadIdx.x;
  const int lane = tid & 63;
  const int w = tid >> 6;
  const int bid = blockIdx.x;
  const int z = bid & ((1 << zshift) - 1);
  const int n0 = (bid >> zshift) * 64;
  const int kbeg = z * kslice;
  const int niters = kslice / BK;
  const int kmax = kbeg + kslice;
  const int fr = lane & 15;
  const int ks = lane >> 4;
  const int m0 = w * 128;
  const bool fullN = (n0 + 64) <= N;

  f32x4 acc[8][4];
#pragma unroll
  for (int i = 0; i < 8; ++i)
#pragma unroll
    for (int j = 0; j < 4; ++j) acc[i][j] = (f32x4){0.f, 0.f, 0.f, 0.f};

  const __bf16* Abase = A + (size_t)(m0 + fr) * K + ks * 8;
  const size_t Astride = (size_t)16 * K;
  const float* Bbase = B + n0 + fr;

  bf16x8 afA[8], afB[8];
  float bA[32], bB[32];

#define LOAD_A(D, t)                                                     \
  {                                                                      \
    int kk = kbeg + (t) * BK;                                            \
    if (kk >= kmax) kk = kbeg;                                           \
    const __bf16* ap = Abase + kk;                                       \
    _Pragma("unroll") for (int i = 0; i < 8; ++i)                        \
        D[i] = *(const bf16x8*)(ap + (size_t)i * Astride);               \
  }

#define LOAD_B(S, t)                                                     \
  {                                                                      \
    int kg = kbeg + (t) * BK;                                            \
    if (kg >= kmax) kg = kbeg;                                           \
    const float* p = Bbase + (size_t)(kg + ks * 8) * N;                  \
    if (fullN) {                                                         \
      _Pragma("unroll") for (int e = 0; e < 8; ++e) {                    \
        _Pragma("unroll") for (int nf = 0; nf < 4; ++nf)                 \
            S[e * 4 + nf] = p[nf * 16];                                  \
        p += N;                                                          \
      }                                                                  \
    } else {                                                             \
      _Pragma("unroll") for (int e = 0; e < 8; ++e) {                    \
        _Pragma("unroll") for (int nf = 0; nf < 4; ++nf)                 \
            S[e * 4 + nf] =                                              \
                (n0 + nf * 16 + fr < N) ? p[nf * 16] : 0.f;              \
        p += N;                                                          \
      }                                                                  \
    }                                                                    \
  }

#define BODY(it, CA, NA, CB)                                             \
  {                                                                      \
    bf16x8 bfr[4];                                                       \
    _Pragma("unroll") for (int e = 0; e < 8; ++e)                        \
        _Pragma("unroll") for (int nf = 0; nf < 4; ++nf)                 \
            bfr[nf][e] = (__bf16)CB[e * 4 + nf];                         \
    LOAD_B(CB, (it) + 2);                                                \
    LOAD_A(NA, (it) + 1);                                                \
    _Pragma("unroll") for (int nf = 0; nf < 4; ++nf)                     \
        _Pragma("unroll") for (int mf = 0; mf < 8; ++mf)                 \
            acc[mf][nf] = __builtin_amdgcn_mfma_f32_16x16x32_bf16(       \
                CA[mf], bfr[nf], acc[mf][nf], 0, 0, 0);                  \
  }

  LOAD_A(afA, 0);
  LOAD_B(bA, 0);
  LOAD_B(bB, 1);
  for (int it = 0; it < niters; it += 2) {
    BODY(it, afA, afB, bA);
    BODY(it + 1, afB, afA, bB);
  }
#undef BODY
#undef LOAD_B
#undef LOAD_A

  const int r0 = ks * 4;
  OutT* pbase = part + (size_t)z * 512 * npad;
#pragma unroll
  for (int mf = 0; mf < 8; ++mf)
#pragma unroll
    for (int nf = 0; nf < 4; ++nf) {
      const int col = n0 + nf * 16 + fr;
#pragma unroll
      for (int r = 0; r < 4; ++r) {
        const int row = m0 + mf * 16 + r0 + r;
        pbase[(size_t)row * npad + col] = (OutT)acc[mf][nf][r];
      }
    }
}

// sum bf16 split-K partials + bias, relu -> bf16 activations [512][4096]
__global__ __launch_bounds__(256) void reduce_relu_kernel(
    const __bf16* __restrict__ part, const float* __restrict__ bias,
    __bf16* __restrict__ out, int nsplit) {
  const int idx = blockIdx.x * 256 + threadIdx.x;
  const int flat = idx * 8;
  if (flat >= 512 * 4096) return;
  float s[8];
#pragma unroll
  for (int j = 0; j < 8; ++j) s[j] = 0.f;
  for (int sp = 0; sp < nsplit; ++sp) {
    bf16x8 v = *(const bf16x8*)(part + (size_t)sp * (512 * 4096) + flat);
#pragma unroll
    for (int j = 0; j < 8; ++j) s[j] += (float)v[j];
  }
  const int nb = flat & 4095;
  bf16x8 o;
#pragma unroll
  for (int j = 0; j < 8; ++j) {
    float v = s[j] + bias[nb + j];
    o[j] = (__bf16)(v > 0.f ? v : 0.f);
  }
  *(bf16x8*)(out + flat) = o;
}

// final: sum split-K fp32 partials (stride 128) + bias -> d_out fp32
__global__ __launch_bounds__(256) void reduce_out_kernel(
    const float* __restrict__ pc, const float* __restrict__ pr,
    const float* __restrict__ bcls, const float* __restrict__ breg,
    float* __restrict__ out, int nsplit) {
  const int gid = blockIdx.x * 256 + threadIdx.x;
  if (gid >= 512 * 105) return;
  if (gid < 512 * 21) {
    const int m = gid / 21, j = gid - m * 21;
    float s = bcls[j];
    for (int sp = 0; sp < nsplit; ++sp)
      s += pc[(size_t)sp * 512 * 128 + m * 128 + j];
    out[gid] = s;
  } else {
    const int g = gid - 512 * 21;
    const int m = g / 84, j = g - m * 84;
    float s = breg[j];
    for (int sp = 0; sp < nsplit; ++sp)
      s += pr[(size_t)sp * 512 * 128 + m * 128 + j];
    out[gid] = s;
  }
}

extern "C" void kernel_launch(void* const* d_in, const int* in_sizes, int n_in,
                              void* d_out, int out_size, void* d_ws, size_t ws_size,
                              hipStream_t stream) {
  (void)in_sizes; (void)n_in; (void)out_size;
  const float* x    = (const float*)d_in[0];
  const float* rois = (const float*)d_in[2];
  const float* W1   = (const float*)d_in[3];
  const float* b1   = (const float*)d_in[4];
  const float* W2   = (const float*)d_in[5];
  const float* b2   = (const float*)d_in[6];
  const float* Wcls = (const float*)d_in[7];
  const float* bcls = (const float*)d_in[8];
  const float* Wreg = (const float*)d_in[9];
  const float* breg = (const float*)d_in[10];
  float* out = (float*)d_out;

  const size_t pooled_b = (size_t)512 * KK1 * 2;        // 25,690,112
  const size_t act_b = (size_t)512 * D1 * 2;            // 4 MiB
  const size_t need8 = pooled_b + (size_t)8 * act_b + 2 * act_b;
  const int ns = (ws_size >= need8) ? 8 : 2;            // ws ~1.6GB: ns=8
  const int zshift = (ns == 8) ? 3 : 1;

  char* ws = (char*)d_ws;
  __bf16* pooled = (__bf16*)ws;
  __bf16* part1 = (__bf16*)(ws + pooled_b);             // ns * 4MiB
  __bf16* f1 = (__bf16*)(ws + pooled_b + (size_t)ns * act_b);
  __bf16* f2 = (__bf16*)(ws + pooled_b + (size_t)ns * act_b + act_b);
  __bf16* part2 = (__bf16*)ws;                          // alias dead pooled+part1
  float* pcls = (float*)ws;                             // heads phase aliases
  float* preg = (float*)(ws + (size_t)64 * 512 * 128 * 4);  // +16.8MB

  // 1) RoIPool -> pooled bf16 [512, 25088]; 16384 blocks for latency hiding
  roipool_kernel<<<N_ROIS * 32, 256, 0, stream>>>(x, rois, pooled);

  // 2) GEMM1: pooled @ W1[25088,4096]; W1 read exactly once; z-pinned XCDs
  gemm_pipe<__bf16><<<32 * ns, 256, 0, stream>>>(
      pooled, W1, part1, 4096, KK1, KK1 / ns, 4096, zshift);
  reduce_relu_kernel<<<1024, 256, 0, stream>>>(part1, b1, f1, ns);

  // 3) GEMM2: f1 @ W2[4096,4096]
  gemm_pipe<__bf16><<<32 * ns, 256, 0, stream>>>(
      f1, W2, part2, 4096, 4096, 4096 / ns, 4096, zshift);
  reduce_relu_kernel<<<1024, 256, 0, stream>>>(part2, b2, f2, ns);

  // 4) heads via gemm_small (N<128-safe), split-K=64
  gemm_small<float><<<64, 256, 0, stream>>>(
      f2, Wcls, pcls, 21, 4096, 64, 128, 6);
  gemm_small<float><<<128, 256, 0, stream>>>(
      f2, Wreg, preg, 84, 4096, 64, 128, 6);
  reduce_out_kernel<<<(512 * 105 + 255) / 256, 256, 0, stream>>>(
      pcls, preg, bcls, breg, out, 64);
}